// Round 1
// baseline (716.751 us; speedup 1.0000x reference)
//
#include <hip/hip_runtime.h>
#include <cstdint>
#include <cstddef>

#define N_NODES 50000
#define N_EDGES 800000
#define DIN_    768
#define H_DIM   128
#define N_REL   3
#define BETA_F  0.05f
#define SLOPE_F 0.2f

static inline int cdiv(int a, int b) { return (a + b - 1) / b; }

// ---------------- CSR build ----------------
__global__ void k_count(const int* __restrict__ dst, int* __restrict__ deg, int E) {
  int e = blockIdx.x * blockDim.x + threadIdx.x;
  if (e < E) atomicAdd(&deg[dst[e]], 1);
}

__global__ __launch_bounds__(1024) void k_scan(const int* __restrict__ deg,
                                               int* __restrict__ off,
                                               int* __restrict__ cur, int n) {
  __shared__ int sums[1024];
  int tid = threadIdx.x;
  int chunk = (n + 1023) >> 10;
  int lo = tid * chunk;
  int hi = lo + chunk; if (hi > n) hi = n; if (lo > n) lo = n;
  int s = 0;
  for (int i = lo; i < hi; ++i) s += deg[i];
  sums[tid] = s;
  __syncthreads();
  for (int d = 1; d < 1024; d <<= 1) {
    int v = (tid >= d) ? sums[tid - d] : 0;
    __syncthreads();
    sums[tid] += v;
    __syncthreads();
  }
  int run = (tid == 0) ? 0 : sums[tid - 1];
  for (int i = lo; i < hi; ++i) {
    off[i] = run; cur[i] = run;
    run += deg[i];
  }
  if (tid == 1023) off[n] = sums[1023];
}

__global__ void k_fill(const int* __restrict__ dst, int* __restrict__ cur,
                       int* __restrict__ csr, int E) {
  int e = blockIdx.x * blockDim.x + threadIdx.x;
  if (e < E) {
    int p = atomicAdd(&cur[dst[e]], 1);
    csr[p] = e;
  }
}

// ---------------- rel scores: rs[t] = (rel[t] @ Wr) @ a_r ----------------
__global__ __launch_bounds__(128) void k_relscore(const float* __restrict__ rel,
                                                  const float* __restrict__ Wr,
                                                  const float* __restrict__ a,
                                                  float* __restrict__ rs) {
  __shared__ float red[128];
  int k = threadIdx.x;
  for (int t = 0; t < N_REL; ++t) {
    float p = 0.f;
    #pragma unroll
    for (int j = 0; j < 32; ++j) p += rel[t * 32 + j] * Wr[j * H_DIM + k];
    red[k] = p * a[2 * H_DIM + k];
    __syncthreads();
    for (int s = 64; s > 0; s >>= 1) {
      if (k < s) red[k] += red[k + s];
      __syncthreads();
    }
    if (k == 0) rs[t] = red[0];
    __syncthreads();
  }
}

// ---------------- GEMM: C[n x 128] = A[n x K] @ B[K x 128] (+bias,relu) ----------------
template <bool BIASRELU>
__global__ __launch_bounds__(256) void k_gemm64(const float* __restrict__ A,
                                                const float* __restrict__ B,
                                                const float* __restrict__ bias,
                                                float* __restrict__ C, int n, int K) {
  __shared__ float As[32][68];    // transposed: As[kk][row], pad 68 (272B, 16B-aligned rows)
  __shared__ float Bs[32][128];
  int tid = threadIdx.x;
  int cg = tid & 15;   // col group: cols cg*8 .. cg*8+7
  int rg = tid >> 4;   // row group: rows rg*4 .. rg*4+3
  int row0 = blockIdx.x * 64;
  float acc[4][8];
  #pragma unroll
  for (int r = 0; r < 4; ++r)
    #pragma unroll
    for (int c = 0; c < 8; ++c) acc[r][c] = 0.f;

  for (int k0 = 0; k0 < K; k0 += 32) {
    for (int i = tid; i < 64 * 32; i += 256) {
      int r = i >> 5, kk = i & 31;
      int gr = row0 + r;
      As[kk][r] = (gr < n) ? A[(size_t)gr * K + k0 + kk] : 0.f;
    }
    for (int i = tid; i < 32 * 128; i += 256) {
      int r = i >> 7, cc = i & 127;
      Bs[r][cc] = B[(size_t)(k0 + r) * 128 + cc];
    }
    __syncthreads();
    #pragma unroll 4
    for (int kk = 0; kk < 32; ++kk) {
      float4 av  = *(const float4*)&As[kk][rg * 4];
      float4 bv0 = *(const float4*)&Bs[kk][cg * 8];
      float4 bv1 = *(const float4*)&Bs[kk][cg * 8 + 4];
      float aa[4] = {av.x, av.y, av.z, av.w};
      float bb[8] = {bv0.x, bv0.y, bv0.z, bv0.w, bv1.x, bv1.y, bv1.z, bv1.w};
      #pragma unroll
      for (int r = 0; r < 4; ++r)
        #pragma unroll
        for (int c = 0; c < 8; ++c)
          acc[r][c] += aa[r] * bb[c];
    }
    __syncthreads();
  }
  #pragma unroll
  for (int r = 0; r < 4; ++r) {
    int gr = row0 + rg * 4 + r;
    if (gr < n) {
      float o[8];
      #pragma unroll
      for (int c = 0; c < 8; ++c) {
        float v = acc[r][c];
        if (BIASRELU) {
          v += bias[cg * 8 + c];
          v = v > 0.f ? v : 0.f;
        }
        o[c] = v;
      }
      *(float4*)&C[(size_t)gr * 128 + cg * 8]     = make_float4(o[0], o[1], o[2], o[3]);
      *(float4*)&C[(size_t)gr * 128 + cg * 8 + 4] = make_float4(o[4], o[5], o[6], o[7]);
    }
  }
}

// ---------------- per-node scores: ni = h@a_i, nj = h@a_j ----------------
__global__ __launch_bounds__(256) void k_scores(const float* __restrict__ h,
                                                const float* __restrict__ a,
                                                float* __restrict__ ni,
                                                float* __restrict__ nj, int n) {
  int lane = threadIdx.x & 63;
  int w = threadIdx.x >> 6;
  int row = blockIdx.x * 4 + w;
  if (row >= n) return;
  float2 v = ((const float2*)(h + (size_t)row * H_DIM))[lane];
  float2 ai = ((const float2*)a)[lane];
  float2 aj = ((const float2*)(a + H_DIM))[lane];
  float si = v.x * ai.x + v.y * ai.y;
  float sj = v.x * aj.x + v.y * aj.y;
  #pragma unroll
  for (int d = 32; d > 0; d >>= 1) {
    si += __shfl_xor(si, d);
    sj += __shfl_xor(sj, d);
  }
  if (lane == 0) { ni[row] = si; nj[row] = sj; }
}

// ---------------- edge logits ----------------
__global__ void k_logit(const int* __restrict__ src, const int* __restrict__ dst,
                        const int* __restrict__ et,
                        const float* __restrict__ ni, const float* __restrict__ nj,
                        const float* __restrict__ rs,
                        float* __restrict__ logit, int E) {
  int e = blockIdx.x * blockDim.x + threadIdx.x;
  if (e >= E) return;
  float v = ni[dst[e]] + nj[src[e]] + rs[et[e]];
  logit[e] = v > 0.f ? v : SLOPE_F * v;
}

// ---------------- per-dst softmax + aggregate + ELU ----------------
// LAYER 0: writes alpha_io[e].  LAYER 1: reads alpha_io[e] (pre_alpha) and mixes.
template <int LAYER>
__global__ __launch_bounds__(128) void k_aggregate(const int* __restrict__ off,
                                                   const int* __restrict__ csr,
                                                   const int* __restrict__ src,
                                                   const float* __restrict__ logit,
                                                   const float* __restrict__ h,
                                                   float* __restrict__ alpha_io,
                                                   float* __restrict__ hout, int n) {
  __shared__ float l_red[2];
  __shared__ float l_alpha[128];
  __shared__ int   l_src[128];
  int nid = blockIdx.x;
  int t = threadIdx.x;
  int lane = t & 63;
  int w = t >> 6;
  int start = off[nid];
  int deg = off[nid + 1] - start;
  float hv = 0.f;
  if (deg > 0) {
    // pass 1: max
    float m = -INFINITY;
    for (int k = t; k < deg; k += 128) m = fmaxf(m, logit[csr[start + k]]);
    #pragma unroll
    for (int d = 32; d > 0; d >>= 1) m = fmaxf(m, __shfl_xor(m, d));
    if (lane == 0) l_red[w] = m;
    __syncthreads();
    m = fmaxf(l_red[0], l_red[1]);
    __syncthreads();
    // pass 2: sum of exp
    float s = 0.f;
    for (int k = t; k < deg; k += 128) s += expf(logit[csr[start + k]] - m);
    #pragma unroll
    for (int d = 32; d > 0; d >>= 1) s += __shfl_xor(s, d);
    if (lane == 0) l_red[w] = s;
    __syncthreads();
    float denom = l_red[0] + l_red[1] + 1e-16f;
    // pass 3: alpha + message accumulation, chunks of 128 edges
    for (int base = 0; base < deg; base += 128) {
      int kk = base + t;
      if (kk < deg) {
        int e = csr[start + kk];
        float al = expf(logit[e] - m) / denom;
        if (LAYER == 1) {
          al = al * (1.f - BETA_F) + BETA_F * alpha_io[e];
        } else {
          alpha_io[e] = al;
        }
        l_alpha[t] = al;
        l_src[t] = src[e];
      }
      __syncthreads();
      int cnt = deg - base; if (cnt > 128) cnt = 128;
      #pragma unroll 4
      for (int k = 0; k < cnt; ++k)
        hv += l_alpha[k] * h[(size_t)l_src[k] * H_DIM + t];
      __syncthreads();
    }
  }
  hout[(size_t)nid * H_DIM + t] = hv > 0.f ? hv : expm1f(hv);
}

// ---------------- final 128->2 projection ----------------
__global__ __launch_bounds__(256) void k_out(const float* __restrict__ P,
                                             const float* __restrict__ ow,
                                             const float* __restrict__ ob,
                                             float* __restrict__ out, int n) {
  int lane = threadIdx.x & 63;
  int w = threadIdx.x >> 6;
  int row = blockIdx.x * 4 + w;
  if (row >= n) return;
  float2 v  = ((const float2*)(P + (size_t)row * H_DIM))[lane];
  float2 w0 = ((const float2*)ow)[2 * lane];      // ow row (2*lane)
  float2 w1 = ((const float2*)ow)[2 * lane + 1];  // ow row (2*lane+1)
  float s0 = v.x * w0.x + v.y * w1.x;
  float s1 = v.x * w0.y + v.y * w1.y;
  #pragma unroll
  for (int d = 32; d > 0; d >>= 1) {
    s0 += __shfl_xor(s0, d);
    s1 += __shfl_xor(s1, d);
  }
  if (lane == 0) {
    out[row * 2]     = s0 + ob[0];
    out[row * 2 + 1] = s1 + ob[1];
  }
}

extern "C" void kernel_launch(void* const* d_in, const int* in_sizes, int n_in,
                              void* d_out, int out_size, void* d_ws, size_t ws_size,
                              hipStream_t stream) {
  const float* x      = (const float*)d_in[0];
  const int*   ei     = (const int*)d_in[1];
  const int*   et     = (const int*)d_in[2];
  const float* W0     = (const float*)d_in[3];
  const float* Wr0    = (const float*)d_in[4];
  const float* a0     = (const float*)d_in[5];
  const float* rel0   = (const float*)d_in[6];
  const float* W1     = (const float*)d_in[7];
  const float* Wr1    = (const float*)d_in[8];
  const float* a1     = (const float*)d_in[9];
  const float* rel1   = (const float*)d_in[10];
  const float* pool_w = (const float*)d_in[11];
  const float* pool_b = (const float*)d_in[12];
  const float* out_w  = (const float*)d_in[13];
  const float* out_b  = (const float*)d_in[14];

  const int* src = ei;            // edge_index[0]
  const int* dst = ei + N_EDGES;  // edge_index[1]

  // ---- workspace layout ----
  char* p = (char*)d_ws;
  auto take = [&](size_t bytes) {
    char* r = p;
    p += (bytes + 511) & ~(size_t)511;
    return r;
  };
  int*   deg    = (int*)take((size_t)N_NODES * 4);
  int*   off    = (int*)take((size_t)(N_NODES + 1) * 4);
  int*   cur    = (int*)take((size_t)N_NODES * 4);
  int*   csr    = (int*)take((size_t)N_EDGES * 4);
  float* logit  = (float*)take((size_t)N_EDGES * 4);
  float* alpha0 = (float*)take((size_t)N_EDGES * 4);
  float* ni     = (float*)take((size_t)N_NODES * 4);
  float* nj     = (float*)take((size_t)N_NODES * 4);
  float* rs     = (float*)take(256);
  float* big1   = (float*)take((size_t)N_NODES * H_DIM * 4);  // h0, later h1b, later pooled
  float* big2   = (float*)take((size_t)N_NODES * H_DIM * 4);  // h1(elu), later h2(elu)

  const int EB = cdiv(N_EDGES, 256);

  // ---- CSR build (per-call; graph inputs are fixed but we must be stateless) ----
  hipMemsetAsync(deg, 0, (size_t)N_NODES * 4, stream);
  k_count<<<EB, 256, 0, stream>>>(dst, deg, N_EDGES);
  k_scan<<<1, 1024, 0, stream>>>(deg, off, cur, N_NODES);
  k_fill<<<EB, 256, 0, stream>>>(dst, cur, csr, N_EDGES);

  // ---- layer 0 ----
  k_relscore<<<1, 128, 0, stream>>>(rel0, Wr0, a0, rs);
  k_gemm64<false><<<cdiv(N_NODES, 64), 256, 0, stream>>>(x, W0, nullptr, big1, N_NODES, DIN_);
  k_scores<<<cdiv(N_NODES, 4), 256, 0, stream>>>(big1, a0, ni, nj, N_NODES);
  k_logit<<<EB, 256, 0, stream>>>(src, dst, et, ni, nj, rs, logit, N_EDGES);
  k_aggregate<0><<<N_NODES, 128, 0, stream>>>(off, csr, src, logit, big1, alpha0, big2, N_NODES);

  // ---- layer 1 ----
  k_relscore<<<1, 128, 0, stream>>>(rel1, Wr1, a1, rs);
  k_gemm64<false><<<cdiv(N_NODES, 64), 256, 0, stream>>>(big2, W1, nullptr, big1, N_NODES, H_DIM);
  k_scores<<<cdiv(N_NODES, 4), 256, 0, stream>>>(big1, a1, ni, nj, N_NODES);
  k_logit<<<EB, 256, 0, stream>>>(src, dst, et, ni, nj, rs, logit, N_EDGES);
  k_aggregate<1><<<N_NODES, 128, 0, stream>>>(off, csr, src, logit, big1, alpha0, big2, N_NODES);

  // ---- head: pooled = relu(h2 @ pool_w + pool_b); out = pooled @ out_w + out_b ----
  k_gemm64<true><<<cdiv(N_NODES, 64), 256, 0, stream>>>(big2, pool_w, pool_b, big1, N_NODES, H_DIM);
  k_out<<<cdiv(N_NODES, 4), 256, 0, stream>>>(big1, out_w, out_b, (float*)d_out, N_NODES);
}

// Round 2
// 529.692 us; speedup vs baseline: 1.3531x; 1.3531x over previous
//
#include <hip/hip_runtime.h>
#include <cstdint>
#include <cstddef>

#define N_NODES 50000
#define N_EDGES 800000
#define DIN_    768
#define H_DIM   128
#define N_REL   3
#define BETA_F  0.05f
#define SLOPE_F 0.2f

static inline int cdiv(int a, int b) { return (a + b - 1) / b; }

typedef __attribute__((ext_vector_type(8))) short bf16x8;
typedef __attribute__((ext_vector_type(8))) unsigned short u16x8;
typedef __attribute__((ext_vector_type(4))) float f32x4;

__device__ __forceinline__ unsigned short f2bf(float f) {
  unsigned u = __builtin_bit_cast(unsigned, f);
  unsigned r = (u + 0x7fffu + ((u >> 16) & 1u)) >> 16;
  return (unsigned short)r;
}
__device__ __forceinline__ float bf2f(unsigned short h) {
  unsigned u = ((unsigned)h) << 16;
  return __builtin_bit_cast(float, u);
}

// ---------------- CSR build ----------------
__global__ void k_count(const int* __restrict__ dst, int* __restrict__ deg, int E) {
  int e = blockIdx.x * blockDim.x + threadIdx.x;
  if (e < E) atomicAdd(&deg[dst[e]], 1);
}

__global__ __launch_bounds__(1024) void k_scan(const int* __restrict__ deg,
                                               int* __restrict__ off,
                                               int* __restrict__ cur, int n) {
  __shared__ int sums[1024];
  int tid = threadIdx.x;
  int chunk = (n + 1023) >> 10;
  int lo = tid * chunk;
  int hi = lo + chunk; if (hi > n) hi = n; if (lo > n) lo = n;
  int s = 0;
  for (int i = lo; i < hi; ++i) s += deg[i];
  sums[tid] = s;
  __syncthreads();
  for (int d = 1; d < 1024; d <<= 1) {
    int v = (tid >= d) ? sums[tid - d] : 0;
    __syncthreads();
    sums[tid] += v;
    __syncthreads();
  }
  int run = (tid == 0) ? 0 : sums[tid - 1];
  for (int i = lo; i < hi; ++i) {
    off[i] = run; cur[i] = run;
    run += deg[i];
  }
  if (tid == 1023) off[n] = sums[1023];
}

__global__ void k_fill(const int* __restrict__ dst, int* __restrict__ cur,
                       int* __restrict__ csr, int E) {
  int e = blockIdx.x * blockDim.x + threadIdx.x;
  if (e < E) {
    int p = atomicAdd(&cur[dst[e]], 1);
    csr[p] = e;
  }
}

// ---------------- rel scores: rs[t] = (rel[t] @ Wr) @ a_r ----------------
__global__ __launch_bounds__(128) void k_relscore(const float* __restrict__ rel,
                                                  const float* __restrict__ Wr,
                                                  const float* __restrict__ a,
                                                  float* __restrict__ rs) {
  __shared__ float red[128];
  int k = threadIdx.x;
  for (int t = 0; t < N_REL; ++t) {
    float p = 0.f;
    #pragma unroll
    for (int j = 0; j < 32; ++j) p += rel[t * 32 + j] * Wr[j * H_DIM + k];
    red[k] = p * a[2 * H_DIM + k];
    __syncthreads();
    for (int s = 64; s > 0; s >>= 1) {
      if (k < s) red[k] += red[k + s];
      __syncthreads();
    }
    if (k == 0) rs[t] = red[0];
    __syncthreads();
  }
}

// ---------------- weight prep: W[K][128] f32 -> Wt_hi/Wt_lo [128][K] bf16 ----------------
__global__ void k_prep(const float* __restrict__ W, int K,
                       short* __restrict__ th, short* __restrict__ tl) {
  int id = blockIdx.x * 256 + threadIdx.x;
  if (id >= K * 128) return;
  int k = id >> 7, c = id & 127;
  float w = W[id];
  unsigned short h = f2bf(w);
  unsigned short l = f2bf(w - bf2f(h));
  th[(size_t)c * K + k] = (short)h;
  tl[(size_t)c * K + k] = (short)l;
}

// ---------------- split-bf16 MFMA GEMM: C[n x 128] = A[n x K] @ B[K x 128] ----------------
// B provided pre-transposed & split: Bt_hi/Bt_lo [128][K] bf16.
// 3-pass: hi*hi + hi*lo + lo*hi ~= f32 accuracy.
#define BM 128
#define BK 64
template <bool BIASRELU>
__global__ __launch_bounds__(256, 2) void k_gemm_mfma(const float* __restrict__ A,
                                                      const short* __restrict__ Bth,
                                                      const short* __restrict__ Btl,
                                                      const float* __restrict__ bias,
                                                      float* __restrict__ C, int n, int K) {
  __shared__ short Ahi[BM * BK], Alo[BM * BK], Bhi[128 * BK], Blo[128 * BK];
  int t = threadIdx.x;
  int l = t & 63, wid = t >> 6;
  int wr = wid >> 1, wc = wid & 1;
  int lr = l & 15, lk = l >> 4;
  int row0 = blockIdx.x * BM;
  f32x4 acc[4][4];
  #pragma unroll
  for (int m = 0; m < 4; ++m)
    #pragma unroll
    for (int nn = 0; nn < 4; ++nn) acc[m][nn] = (f32x4)(0.f);

  for (int k0 = 0; k0 < K; k0 += BK) {
    // ---- stage A (f32 -> hi/lo bf16, XOR-swizzled granules) ----
    #pragma unroll
    for (int i = 0; i < 4; ++i) {
      int gid = i * 256 + t;          // 1024 granules of 8
      int r = gid >> 3, g = gid & 7;
      int gr = row0 + r;
      float4 v0 = make_float4(0.f, 0.f, 0.f, 0.f);
      float4 v1 = make_float4(0.f, 0.f, 0.f, 0.f);
      if (gr < n) {
        const float* ap = A + (size_t)gr * K + k0 + g * 8;
        v0 = *(const float4*)ap;
        v1 = *(const float4*)(ap + 4);
      }
      float f[8] = {v0.x, v0.y, v0.z, v0.w, v1.x, v1.y, v1.z, v1.w};
      u16x8 hv, lv;
      #pragma unroll
      for (int j = 0; j < 8; ++j) {
        unsigned short h = f2bf(f[j]);
        hv[j] = h;
        lv[j] = f2bf(f[j] - bf2f(h));
      }
      int sg = (g ^ (r & 7)) << 3;
      *(u16x8*)&Ahi[r * BK + sg] = hv;
      *(u16x8*)&Alo[r * BK + sg] = lv;
    }
    // ---- stage B (pre-split bf16, XOR-swizzled) ----
    #pragma unroll
    for (int i = 0; i < 4; ++i) {
      int gid = i * 256 + t;
      int c = gid >> 3, g = gid & 7;
      u16x8 hv = *(const u16x8*)(Bth + (size_t)c * K + k0 + g * 8);
      u16x8 lv = *(const u16x8*)(Btl + (size_t)c * K + k0 + g * 8);
      int sg = (g ^ (c & 7)) << 3;
      *(u16x8*)&Bhi[c * BK + sg] = hv;
      *(u16x8*)&Blo[c * BK + sg] = lv;
    }
    __syncthreads();
    // ---- MFMA ----
    #pragma unroll
    for (int kk = 0; kk < 2; ++kk) {
      int gbase = kk * 4 + lk;        // this lane's k-granule
      bf16x8 ah[4], al[4], bh[4], bl[4];
      #pragma unroll
      for (int m = 0; m < 4; ++m) {
        int r = wr * 64 + m * 16 + lr;
        int idx = r * BK + ((gbase ^ (r & 7)) << 3);
        ah[m] = *(const bf16x8*)&Ahi[idx];
        al[m] = *(const bf16x8*)&Alo[idx];
      }
      #pragma unroll
      for (int nn = 0; nn < 4; ++nn) {
        int c = wc * 64 + nn * 16 + lr;
        int idx = c * BK + ((gbase ^ (c & 7)) << 3);
        bh[nn] = *(const bf16x8*)&Bhi[idx];
        bl[nn] = *(const bf16x8*)&Blo[idx];
      }
      #pragma unroll
      for (int m = 0; m < 4; ++m)
        #pragma unroll
        for (int nn = 0; nn < 4; ++nn) {
          acc[m][nn] = __builtin_amdgcn_mfma_f32_16x16x32_bf16(ah[m], bh[nn], acc[m][nn], 0, 0, 0);
          acc[m][nn] = __builtin_amdgcn_mfma_f32_16x16x32_bf16(ah[m], bl[nn], acc[m][nn], 0, 0, 0);
          acc[m][nn] = __builtin_amdgcn_mfma_f32_16x16x32_bf16(al[m], bh[nn], acc[m][nn], 0, 0, 0);
        }
    }
    __syncthreads();
  }
  // ---- epilogue: C/D layout col=lane&15, row=(lane>>4)*4+q ----
  #pragma unroll
  for (int m = 0; m < 4; ++m) {
    int rbase = row0 + wr * 64 + m * 16 + lk * 4;
    #pragma unroll
    for (int nn = 0; nn < 4; ++nn) {
      int c = wc * 64 + nn * 16 + lr;
      #pragma unroll
      for (int q = 0; q < 4; ++q) {
        int r = rbase + q;
        if (r < n) {
          float v = acc[m][nn][q];
          if (BIASRELU) {
            v += bias[c];
            v = v > 0.f ? v : 0.f;
          }
          C[(size_t)r * 128 + c] = v;
        }
      }
    }
  }
}

// ---------------- per-node scores: ni = h@a_i, nj = h@a_j ----------------
__global__ __launch_bounds__(256) void k_scores(const float* __restrict__ h,
                                                const float* __restrict__ a,
                                                float* __restrict__ ni,
                                                float* __restrict__ nj, int n) {
  int lane = threadIdx.x & 63;
  int w = threadIdx.x >> 6;
  int row = blockIdx.x * 4 + w;
  if (row >= n) return;
  float2 v = ((const float2*)(h + (size_t)row * H_DIM))[lane];
  float2 ai = ((const float2*)a)[lane];
  float2 aj = ((const float2*)(a + H_DIM))[lane];
  float si = v.x * ai.x + v.y * ai.y;
  float sj = v.x * aj.x + v.y * aj.y;
  #pragma unroll
  for (int d = 32; d > 0; d >>= 1) {
    si += __shfl_xor(si, d);
    sj += __shfl_xor(sj, d);
  }
  if (lane == 0) { ni[row] = si; nj[row] = sj; }
}

// ---------------- edge logits ----------------
__global__ void k_logit(const int* __restrict__ src, const int* __restrict__ dst,
                        const int* __restrict__ et,
                        const float* __restrict__ ni, const float* __restrict__ nj,
                        const float* __restrict__ rs,
                        float* __restrict__ logit, int E) {
  int e = blockIdx.x * blockDim.x + threadIdx.x;
  if (e >= E) return;
  float v = ni[dst[e]] + nj[src[e]] + rs[et[e]];
  logit[e] = v > 0.f ? v : SLOPE_F * v;
}

// ---------------- per-dst softmax + aggregate + ELU ----------------
template <int LAYER>
__global__ __launch_bounds__(128) void k_aggregate(const int* __restrict__ off,
                                                   const int* __restrict__ csr,
                                                   const int* __restrict__ src,
                                                   const float* __restrict__ logit,
                                                   const float* __restrict__ h,
                                                   float* __restrict__ alpha_io,
                                                   float* __restrict__ hout, int n) {
  __shared__ float l_red[2];
  __shared__ float l_alpha[128];
  __shared__ int   l_src[128];
  int nid = blockIdx.x;
  int t = threadIdx.x;
  int lane = t & 63;
  int w = t >> 6;
  int start = off[nid];
  int deg = off[nid + 1] - start;
  float hv = 0.f;
  if (deg > 0) {
    float m = -INFINITY;
    for (int k = t; k < deg; k += 128) m = fmaxf(m, logit[csr[start + k]]);
    #pragma unroll
    for (int d = 32; d > 0; d >>= 1) m = fmaxf(m, __shfl_xor(m, d));
    if (lane == 0) l_red[w] = m;
    __syncthreads();
    m = fmaxf(l_red[0], l_red[1]);
    __syncthreads();
    float s = 0.f;
    for (int k = t; k < deg; k += 128) s += expf(logit[csr[start + k]] - m);
    #pragma unroll
    for (int d = 32; d > 0; d >>= 1) s += __shfl_xor(s, d);
    if (lane == 0) l_red[w] = s;
    __syncthreads();
    float denom = l_red[0] + l_red[1] + 1e-16f;
    for (int base = 0; base < deg; base += 128) {
      int kk = base + t;
      if (kk < deg) {
        int e = csr[start + kk];
        float al = expf(logit[e] - m) / denom;
        if (LAYER == 1) {
          al = al * (1.f - BETA_F) + BETA_F * alpha_io[e];
        } else {
          alpha_io[e] = al;
        }
        l_alpha[t] = al;
        l_src[t] = src[e];
      }
      __syncthreads();
      int cnt = deg - base; if (cnt > 128) cnt = 128;
      #pragma unroll 4
      for (int k = 0; k < cnt; ++k)
        hv += l_alpha[k] * h[(size_t)l_src[k] * H_DIM + t];
      __syncthreads();
    }
  }
  hout[(size_t)nid * H_DIM + t] = hv > 0.f ? hv : expm1f(hv);
}

// ---------------- final 128->2 projection ----------------
__global__ __launch_bounds__(256) void k_out(const float* __restrict__ P,
                                             const float* __restrict__ ow,
                                             const float* __restrict__ ob,
                                             float* __restrict__ out, int n) {
  int lane = threadIdx.x & 63;
  int w = threadIdx.x >> 6;
  int row = blockIdx.x * 4 + w;
  if (row >= n) return;
  float2 v  = ((const float2*)(P + (size_t)row * H_DIM))[lane];
  float2 w0 = ((const float2*)ow)[2 * lane];
  float2 w1 = ((const float2*)ow)[2 * lane + 1];
  float s0 = v.x * w0.x + v.y * w1.x;
  float s1 = v.x * w0.y + v.y * w1.y;
  #pragma unroll
  for (int d = 32; d > 0; d >>= 1) {
    s0 += __shfl_xor(s0, d);
    s1 += __shfl_xor(s1, d);
  }
  if (lane == 0) {
    out[row * 2]     = s0 + ob[0];
    out[row * 2 + 1] = s1 + ob[1];
  }
}

extern "C" void kernel_launch(void* const* d_in, const int* in_sizes, int n_in,
                              void* d_out, int out_size, void* d_ws, size_t ws_size,
                              hipStream_t stream) {
  const float* x      = (const float*)d_in[0];
  const int*   ei     = (const int*)d_in[1];
  const int*   et     = (const int*)d_in[2];
  const float* W0     = (const float*)d_in[3];
  const float* Wr0    = (const float*)d_in[4];
  const float* a0     = (const float*)d_in[5];
  const float* rel0   = (const float*)d_in[6];
  const float* W1     = (const float*)d_in[7];
  const float* Wr1    = (const float*)d_in[8];
  const float* a1     = (const float*)d_in[9];
  const float* rel1   = (const float*)d_in[10];
  const float* pool_w = (const float*)d_in[11];
  const float* pool_b = (const float*)d_in[12];
  const float* out_w  = (const float*)d_in[13];
  const float* out_b  = (const float*)d_in[14];

  const int* src = ei;            // edge_index[0]
  const int* dst = ei + N_EDGES;  // edge_index[1]

  // ---- workspace layout ----
  char* p = (char*)d_ws;
  auto take = [&](size_t bytes) {
    char* r = p;
    p += (bytes + 511) & ~(size_t)511;
    return r;
  };
  int*   deg    = (int*)take((size_t)N_NODES * 4);
  int*   off    = (int*)take((size_t)(N_NODES + 1) * 4);
  int*   cur    = (int*)take((size_t)N_NODES * 4);
  int*   csr    = (int*)take((size_t)N_EDGES * 4);
  float* logit  = (float*)take((size_t)N_EDGES * 4);
  float* alpha0 = (float*)take((size_t)N_EDGES * 4);
  float* ni     = (float*)take((size_t)N_NODES * 4);
  float* nj     = (float*)take((size_t)N_NODES * 4);
  float* rs     = (float*)take(256);
  short* wt0h   = (short*)take((size_t)DIN_ * 128 * 2);
  short* wt0l   = (short*)take((size_t)DIN_ * 128 * 2);
  short* wt1h   = (short*)take((size_t)128 * 128 * 2);
  short* wt1l   = (short*)take((size_t)128 * 128 * 2);
  short* wph    = (short*)take((size_t)128 * 128 * 2);
  short* wpl    = (short*)take((size_t)128 * 128 * 2);
  float* big1   = (float*)take((size_t)N_NODES * H_DIM * 4);
  float* big2   = (float*)take((size_t)N_NODES * H_DIM * 4);

  const int EB = cdiv(N_EDGES, 256);
  const int GB = cdiv(N_NODES, BM);

  // ---- CSR build ----
  hipMemsetAsync(deg, 0, (size_t)N_NODES * 4, stream);
  k_count<<<EB, 256, 0, stream>>>(dst, deg, N_EDGES);
  k_scan<<<1, 1024, 0, stream>>>(deg, off, cur, N_NODES);
  k_fill<<<EB, 256, 0, stream>>>(dst, cur, csr, N_EDGES);

  // ---- weight prep (transpose + bf16 hi/lo split) ----
  k_prep<<<cdiv(DIN_ * 128, 256), 256, 0, stream>>>(W0, DIN_, wt0h, wt0l);
  k_prep<<<cdiv(128 * 128, 256), 256, 0, stream>>>(W1, 128, wt1h, wt1l);
  k_prep<<<cdiv(128 * 128, 256), 256, 0, stream>>>(pool_w, 128, wph, wpl);

  // ---- layer 0 ----
  k_relscore<<<1, 128, 0, stream>>>(rel0, Wr0, a0, rs);
  k_gemm_mfma<false><<<GB, 256, 0, stream>>>(x, wt0h, wt0l, nullptr, big1, N_NODES, DIN_);
  k_scores<<<cdiv(N_NODES, 4), 256, 0, stream>>>(big1, a0, ni, nj, N_NODES);
  k_logit<<<EB, 256, 0, stream>>>(src, dst, et, ni, nj, rs, logit, N_EDGES);
  k_aggregate<0><<<N_NODES, 128, 0, stream>>>(off, csr, src, logit, big1, alpha0, big2, N_NODES);

  // ---- layer 1 ----
  k_relscore<<<1, 128, 0, stream>>>(rel1, Wr1, a1, rs);
  k_gemm_mfma<false><<<GB, 256, 0, stream>>>(big2, wt1h, wt1l, nullptr, big1, N_NODES, 128);
  k_scores<<<cdiv(N_NODES, 4), 256, 0, stream>>>(big1, a1, ni, nj, N_NODES);
  k_logit<<<EB, 256, 0, stream>>>(src, dst, et, ni, nj, rs, logit, N_EDGES);
  k_aggregate<1><<<N_NODES, 128, 0, stream>>>(off, csr, src, logit, big1, alpha0, big2, N_NODES);

  // ---- head ----
  k_gemm_mfma<true><<<GB, 256, 0, stream>>>(big2, wph, wpl, pool_b, big1, N_NODES, 128);
  k_out<<<cdiv(N_NODES, 4), 256, 0, stream>>>(big1, out_w, out_b, (float*)d_out, N_NODES);
}

// Round 3
// 426.979 us; speedup vs baseline: 1.6787x; 1.2406x over previous
//
#include <hip/hip_runtime.h>
#include <cstdint>
#include <cstddef>

#define N_NODES 50000
#define N_EDGES 800000
#define DIN_    768
#define H_DIM   128
#define N_REL   3
#define BETA_F  0.05f
#define SLOPE_F 0.2f

static inline int cdiv(int a, int b) { return (a + b - 1) / b; }

typedef __attribute__((ext_vector_type(8))) short bf16x8;
typedef __attribute__((ext_vector_type(8))) unsigned short u16x8;
typedef __attribute__((ext_vector_type(4))) float f32x4;

__device__ __forceinline__ unsigned short f2bf(float f) {
  unsigned u = __builtin_bit_cast(unsigned, f);
  unsigned r = (u + 0x7fffu + ((u >> 16) & 1u)) >> 16;
  return (unsigned short)r;
}
__device__ __forceinline__ float bf2f(unsigned short h) {
  unsigned u = ((unsigned)h) << 16;
  return __builtin_bit_cast(float, u);
}

// ---------------- CSR build ----------------
__global__ void k_count(const int* __restrict__ dst, int* __restrict__ deg, int E) {
  int e = blockIdx.x * blockDim.x + threadIdx.x;
  if (e < E) atomicAdd(&deg[dst[e]], 1);
}

// 3-stage hierarchical exclusive scan over deg[0..n) -> off/cur, off[n]=total.
__global__ __launch_bounds__(256) void k_scan1(const int* __restrict__ deg,
                                               int* __restrict__ part, int n) {
  __shared__ int wsum[4];
  int i = blockIdx.x * 256 + threadIdx.x;
  int lane = threadIdx.x & 63, w = threadIdx.x >> 6;
  int v = (i < n) ? deg[i] : 0;
  #pragma unroll
  for (int d = 32; d > 0; d >>= 1) v += __shfl_xor(v, d);
  if (lane == 0) wsum[w] = v;
  __syncthreads();
  if (threadIdx.x == 0) part[blockIdx.x] = wsum[0] + wsum[1] + wsum[2] + wsum[3];
}

__global__ __launch_bounds__(256) void k_scan2(int* __restrict__ part,
                                               int* __restrict__ off, int nb, int n) {
  __shared__ int sh[256];
  int t = threadIdx.x;
  int v = (t < nb) ? part[t] : 0;
  int incl = v;
  sh[t] = incl;
  __syncthreads();
  #pragma unroll
  for (int d = 1; d < 256; d <<= 1) {
    int u = (t >= d) ? sh[t - d] : 0;
    __syncthreads();
    sh[t] += u;
    __syncthreads();
  }
  incl = sh[t];
  if (t < nb) part[t] = incl - v;          // exclusive block prefix
  if (t == nb - 1) off[n] = incl;          // grand total
}

__global__ __launch_bounds__(256) void k_scan3(const int* __restrict__ deg,
                                               const int* __restrict__ part,
                                               int* __restrict__ off,
                                               int* __restrict__ cur, int n) {
  __shared__ int wsum[4];
  int i = blockIdx.x * 256 + threadIdx.x;
  int lane = threadIdx.x & 63, w = threadIdx.x >> 6;
  int v = (i < n) ? deg[i] : 0;
  int incl = v;
  #pragma unroll
  for (int d = 1; d < 64; d <<= 1) {
    int u = __shfl_up(incl, d);
    if (lane >= d) incl += u;
  }
  if (lane == 63) wsum[w] = incl;
  __syncthreads();
  int woff = 0;
  #pragma unroll
  for (int k = 0; k < 4; ++k) woff += (k < w) ? wsum[k] : 0;
  int ex = incl - v + woff + part[blockIdx.x];
  if (i < n) { off[i] = ex; cur[i] = ex; }
}

__global__ void k_fill(const int* __restrict__ dst, int* __restrict__ cur,
                       int* __restrict__ csr, int E) {
  int e = blockIdx.x * blockDim.x + threadIdx.x;
  if (e < E) {
    int p = atomicAdd(&cur[dst[e]], 1);
    csr[p] = e;
  }
}

// ---------------- rel scores: rs[t] = (rel[t] @ Wr) @ a_r ----------------
__global__ __launch_bounds__(128) void k_relscore(const float* __restrict__ rel,
                                                  const float* __restrict__ Wr,
                                                  const float* __restrict__ a,
                                                  float* __restrict__ rs) {
  __shared__ float red[128];
  int k = threadIdx.x;
  for (int t = 0; t < N_REL; ++t) {
    float p = 0.f;
    #pragma unroll
    for (int j = 0; j < 32; ++j) p += rel[t * 32 + j] * Wr[j * H_DIM + k];
    red[k] = p * a[2 * H_DIM + k];
    __syncthreads();
    for (int s = 64; s > 0; s >>= 1) {
      if (k < s) red[k] += red[k + s];
      __syncthreads();
    }
    if (k == 0) rs[t] = red[0];
    __syncthreads();
  }
}

// ---------------- weight prep: W[K][128] f32 -> Wt_hi/Wt_lo [128][K] bf16 ----------------
__global__ void k_prep(const float* __restrict__ W, int K,
                       short* __restrict__ th, short* __restrict__ tl) {
  int id = blockIdx.x * 256 + threadIdx.x;
  if (id >= K * 128) return;
  int k = id >> 7, c = id & 127;
  float w = W[id];
  unsigned short h = f2bf(w);
  unsigned short l = f2bf(w - bf2f(h));
  th[(size_t)c * K + k] = (short)h;
  tl[(size_t)c * K + k] = (short)l;
}

// ---------------- split-bf16 MFMA GEMM: C[n x 128] = A[n x K] @ B[K x 128] ----------------
#define BM 128
#define BK 64
template <bool BIASRELU>
__global__ __launch_bounds__(256, 2) void k_gemm_mfma(const float* __restrict__ A,
                                                      const short* __restrict__ Bth,
                                                      const short* __restrict__ Btl,
                                                      const float* __restrict__ bias,
                                                      float* __restrict__ C, int n, int K) {
  __shared__ short Ahi[BM * BK], Alo[BM * BK], Bhi[128 * BK], Blo[128 * BK];
  int t = threadIdx.x;
  int l = t & 63, wid = t >> 6;
  int wr = wid >> 1, wc = wid & 1;
  int lr = l & 15, lk = l >> 4;
  int row0 = blockIdx.x * BM;
  f32x4 acc[4][4];
  #pragma unroll
  for (int m = 0; m < 4; ++m)
    #pragma unroll
    for (int nn = 0; nn < 4; ++nn) acc[m][nn] = (f32x4)(0.f);

  for (int k0 = 0; k0 < K; k0 += BK) {
    #pragma unroll
    for (int i = 0; i < 4; ++i) {
      int gid = i * 256 + t;
      int r = gid >> 3, g = gid & 7;
      int gr = row0 + r;
      float4 v0 = make_float4(0.f, 0.f, 0.f, 0.f);
      float4 v1 = make_float4(0.f, 0.f, 0.f, 0.f);
      if (gr < n) {
        const float* ap = A + (size_t)gr * K + k0 + g * 8;
        v0 = *(const float4*)ap;
        v1 = *(const float4*)(ap + 4);
      }
      float f[8] = {v0.x, v0.y, v0.z, v0.w, v1.x, v1.y, v1.z, v1.w};
      u16x8 hv, lv;
      #pragma unroll
      for (int j = 0; j < 8; ++j) {
        unsigned short h = f2bf(f[j]);
        hv[j] = h;
        lv[j] = f2bf(f[j] - bf2f(h));
      }
      int sg = (g ^ (r & 7)) << 3;
      *(u16x8*)&Ahi[r * BK + sg] = hv;
      *(u16x8*)&Alo[r * BK + sg] = lv;
    }
    #pragma unroll
    for (int i = 0; i < 4; ++i) {
      int gid = i * 256 + t;
      int c = gid >> 3, g = gid & 7;
      u16x8 hv = *(const u16x8*)(Bth + (size_t)c * K + k0 + g * 8);
      u16x8 lv = *(const u16x8*)(Btl + (size_t)c * K + k0 + g * 8);
      int sg = (g ^ (c & 7)) << 3;
      *(u16x8*)&Bhi[c * BK + sg] = hv;
      *(u16x8*)&Blo[c * BK + sg] = lv;
    }
    __syncthreads();
    #pragma unroll
    for (int kk = 0; kk < 2; ++kk) {
      int gbase = kk * 4 + lk;
      bf16x8 ah[4], al[4], bh[4], bl[4];
      #pragma unroll
      for (int m = 0; m < 4; ++m) {
        int r = wr * 64 + m * 16 + lr;
        int idx = r * BK + ((gbase ^ (r & 7)) << 3);
        ah[m] = *(const bf16x8*)&Ahi[idx];
        al[m] = *(const bf16x8*)&Alo[idx];
      }
      #pragma unroll
      for (int nn = 0; nn < 4; ++nn) {
        int c = wc * 64 + nn * 16 + lr;
        int idx = c * BK + ((gbase ^ (c & 7)) << 3);
        bh[nn] = *(const bf16x8*)&Bhi[idx];
        bl[nn] = *(const bf16x8*)&Blo[idx];
      }
      #pragma unroll
      for (int m = 0; m < 4; ++m)
        #pragma unroll
        for (int nn = 0; nn < 4; ++nn) {
          acc[m][nn] = __builtin_amdgcn_mfma_f32_16x16x32_bf16(ah[m], bh[nn], acc[m][nn], 0, 0, 0);
          acc[m][nn] = __builtin_amdgcn_mfma_f32_16x16x32_bf16(ah[m], bl[nn], acc[m][nn], 0, 0, 0);
          acc[m][nn] = __builtin_amdgcn_mfma_f32_16x16x32_bf16(al[m], bh[nn], acc[m][nn], 0, 0, 0);
        }
    }
    __syncthreads();
  }
  #pragma unroll
  for (int m = 0; m < 4; ++m) {
    int rbase = row0 + wr * 64 + m * 16 + lk * 4;
    #pragma unroll
    for (int nn = 0; nn < 4; ++nn) {
      int c = wc * 64 + nn * 16 + lr;
      #pragma unroll
      for (int q = 0; q < 4; ++q) {
        int r = rbase + q;
        if (r < n) {
          float v = acc[m][nn][q];
          if (BIASRELU) {
            v += bias[c];
            v = v > 0.f ? v : 0.f;
          }
          C[(size_t)r * 128 + c] = v;
        }
      }
    }
  }
}

// ---------------- per-node scores: ni = h@a_i, nj = h@a_j ----------------
__global__ __launch_bounds__(256) void k_scores(const float* __restrict__ h,
                                                const float* __restrict__ a,
                                                float* __restrict__ ni,
                                                float* __restrict__ nj, int n) {
  int lane = threadIdx.x & 63;
  int w = threadIdx.x >> 6;
  int row = blockIdx.x * 4 + w;
  if (row >= n) return;
  float2 v = ((const float2*)(h + (size_t)row * H_DIM))[lane];
  float2 ai = ((const float2*)a)[lane];
  float2 aj = ((const float2*)(a + H_DIM))[lane];
  float si = v.x * ai.x + v.y * ai.y;
  float sj = v.x * aj.x + v.y * aj.y;
  #pragma unroll
  for (int d = 32; d > 0; d >>= 1) {
    si += __shfl_xor(si, d);
    sj += __shfl_xor(sj, d);
  }
  if (lane == 0) { ni[row] = si; nj[row] = sj; }
}

// ---------------- edge logits ----------------
__global__ void k_logit(const int* __restrict__ src, const int* __restrict__ dst,
                        const int* __restrict__ et,
                        const float* __restrict__ ni, const float* __restrict__ nj,
                        const float* __restrict__ rs,
                        float* __restrict__ logit, int E) {
  int e = blockIdx.x * blockDim.x + threadIdx.x;
  if (e >= E) return;
  float v = ni[dst[e]] + nj[src[e]] + rs[et[e]];
  logit[e] = v > 0.f ? v : SLOPE_F * v;
}

// ---------------- per-dst softmax + aggregate + ELU ----------------
template <int LAYER>
__global__ __launch_bounds__(128) void k_aggregate(const int* __restrict__ off,
                                                   const int* __restrict__ csr,
                                                   const int* __restrict__ src,
                                                   const float* __restrict__ logit,
                                                   const float* __restrict__ h,
                                                   float* __restrict__ alpha_io,
                                                   float* __restrict__ hout, int n) {
  __shared__ float l_red[2];
  __shared__ float l_alpha[128];
  __shared__ int   l_src[128];
  int nid = blockIdx.x;
  int t = threadIdx.x;
  int lane = t & 63;
  int w = t >> 6;
  int start = off[nid];
  int deg = off[nid + 1] - start;
  float hv = 0.f;
  if (deg > 0) {
    float m = -INFINITY;
    for (int k = t; k < deg; k += 128) m = fmaxf(m, logit[csr[start + k]]);
    #pragma unroll
    for (int d = 32; d > 0; d >>= 1) m = fmaxf(m, __shfl_xor(m, d));
    if (lane == 0) l_red[w] = m;
    __syncthreads();
    m = fmaxf(l_red[0], l_red[1]);
    __syncthreads();
    float s = 0.f;
    for (int k = t; k < deg; k += 128) s += expf(logit[csr[start + k]] - m);
    #pragma unroll
    for (int d = 32; d > 0; d >>= 1) s += __shfl_xor(s, d);
    if (lane == 0) l_red[w] = s;
    __syncthreads();
    float denom = l_red[0] + l_red[1] + 1e-16f;
    for (int base = 0; base < deg; base += 128) {
      int kk = base + t;
      if (kk < deg) {
        int e = csr[start + kk];
        float al = expf(logit[e] - m) / denom;
        if (LAYER == 1) {
          al = al * (1.f - BETA_F) + BETA_F * alpha_io[e];
        } else {
          alpha_io[e] = al;
        }
        l_alpha[t] = al;
        l_src[t] = src[e];
      }
      __syncthreads();
      int cnt = deg - base; if (cnt > 128) cnt = 128;
      #pragma unroll 4
      for (int k = 0; k < cnt; ++k)
        hv += l_alpha[k] * h[(size_t)l_src[k] * H_DIM + t];
      __syncthreads();
    }
  }
  hout[(size_t)nid * H_DIM + t] = hv > 0.f ? hv : expm1f(hv);
}

// ---------------- final 128->2 projection ----------------
__global__ __launch_bounds__(256) void k_out(const float* __restrict__ P,
                                             const float* __restrict__ ow,
                                             const float* __restrict__ ob,
                                             float* __restrict__ out, int n) {
  int lane = threadIdx.x & 63;
  int w = threadIdx.x >> 6;
  int row = blockIdx.x * 4 + w;
  if (row >= n) return;
  float2 v  = ((const float2*)(P + (size_t)row * H_DIM))[lane];
  float2 w0 = ((const float2*)ow)[2 * lane];
  float2 w1 = ((const float2*)ow)[2 * lane + 1];
  float s0 = v.x * w0.x + v.y * w1.x;
  float s1 = v.x * w0.y + v.y * w1.y;
  #pragma unroll
  for (int d = 32; d > 0; d >>= 1) {
    s0 += __shfl_xor(s0, d);
    s1 += __shfl_xor(s1, d);
  }
  if (lane == 0) {
    out[row * 2]     = s0 + ob[0];
    out[row * 2 + 1] = s1 + ob[1];
  }
}

extern "C" void kernel_launch(void* const* d_in, const int* in_sizes, int n_in,
                              void* d_out, int out_size, void* d_ws, size_t ws_size,
                              hipStream_t stream) {
  const float* x      = (const float*)d_in[0];
  const int*   ei     = (const int*)d_in[1];
  const int*   et     = (const int*)d_in[2];
  const float* W0     = (const float*)d_in[3];
  const float* Wr0    = (const float*)d_in[4];
  const float* a0     = (const float*)d_in[5];
  const float* rel0   = (const float*)d_in[6];
  const float* W1     = (const float*)d_in[7];
  const float* Wr1    = (const float*)d_in[8];
  const float* a1     = (const float*)d_in[9];
  const float* rel1   = (const float*)d_in[10];
  const float* pool_w = (const float*)d_in[11];
  const float* pool_b = (const float*)d_in[12];
  const float* out_w  = (const float*)d_in[13];
  const float* out_b  = (const float*)d_in[14];

  const int* src = ei;
  const int* dst = ei + N_EDGES;

  char* p = (char*)d_ws;
  auto take = [&](size_t bytes) {
    char* r = p;
    p += (bytes + 511) & ~(size_t)511;
    return r;
  };
  int*   deg    = (int*)take((size_t)N_NODES * 4);
  int*   off    = (int*)take((size_t)(N_NODES + 1) * 4);
  int*   cur    = (int*)take((size_t)N_NODES * 4);
  int*   part   = (int*)take((size_t)256 * 4);
  int*   csr    = (int*)take((size_t)N_EDGES * 4);
  float* logit  = (float*)take((size_t)N_EDGES * 4);
  float* alpha0 = (float*)take((size_t)N_EDGES * 4);
  float* ni     = (float*)take((size_t)N_NODES * 4);
  float* nj     = (float*)take((size_t)N_NODES * 4);
  float* rs     = (float*)take(256);
  short* wt0h   = (short*)take((size_t)DIN_ * 128 * 2);
  short* wt0l   = (short*)take((size_t)DIN_ * 128 * 2);
  short* wt1h   = (short*)take((size_t)128 * 128 * 2);
  short* wt1l   = (short*)take((size_t)128 * 128 * 2);
  short* wph    = (short*)take((size_t)128 * 128 * 2);
  short* wpl    = (short*)take((size_t)128 * 128 * 2);
  float* big1   = (float*)take((size_t)N_NODES * H_DIM * 4);
  float* big2   = (float*)take((size_t)N_NODES * H_DIM * 4);

  const int EB = cdiv(N_EDGES, 256);
  const int GB = cdiv(N_NODES, BM);
  const int SB = cdiv(N_NODES, 256);   // 196 scan blocks

  // ---- CSR build ----
  hipMemsetAsync(deg, 0, (size_t)N_NODES * 4, stream);
  k_count<<<EB, 256, 0, stream>>>(dst, deg, N_EDGES);
  k_scan1<<<SB, 256, 0, stream>>>(deg, part, N_NODES);
  k_scan2<<<1, 256, 0, stream>>>(part, off, SB, N_NODES);
  k_scan3<<<SB, 256, 0, stream>>>(deg, part, off, cur, N_NODES);
  k_fill<<<EB, 256, 0, stream>>>(dst, cur, csr, N_EDGES);

  // ---- weight prep ----
  k_prep<<<cdiv(DIN_ * 128, 256), 256, 0, stream>>>(W0, DIN_, wt0h, wt0l);
  k_prep<<<cdiv(128 * 128, 256), 256, 0, stream>>>(W1, 128, wt1h, wt1l);
  k_prep<<<cdiv(128 * 128, 256), 256, 0, stream>>>(pool_w, 128, wph, wpl);

  // ---- layer 0 ----
  k_relscore<<<1, 128, 0, stream>>>(rel0, Wr0, a0, rs);
  k_gemm_mfma<false><<<GB, 256, 0, stream>>>(x, wt0h, wt0l, nullptr, big1, N_NODES, DIN_);
  k_scores<<<cdiv(N_NODES, 4), 256, 0, stream>>>(big1, a0, ni, nj, N_NODES);
  k_logit<<<EB, 256, 0, stream>>>(src, dst, et, ni, nj, rs, logit, N_EDGES);
  k_aggregate<0><<<N_NODES, 128, 0, stream>>>(off, csr, src, logit, big1, alpha0, big2, N_NODES);

  // ---- layer 1 ----
  k_relscore<<<1, 128, 0, stream>>>(rel1, Wr1, a1, rs);
  k_gemm_mfma<false><<<GB, 256, 0, stream>>>(big2, wt1h, wt1l, nullptr, big1, N_NODES, 128);
  k_scores<<<cdiv(N_NODES, 4), 256, 0, stream>>>(big1, a1, ni, nj, N_NODES);
  k_logit<<<EB, 256, 0, stream>>>(src, dst, et, ni, nj, rs, logit, N_EDGES);
  k_aggregate<1><<<N_NODES, 128, 0, stream>>>(off, csr, src, logit, big1, alpha0, big2, N_NODES);

  // ---- head ----
  k_gemm_mfma<true><<<GB, 256, 0, stream>>>(big2, wph, wpl, pool_b, big1, N_NODES, 128);
  k_out<<<cdiv(N_NODES, 4), 256, 0, stream>>>(big1, out_w, out_b, (float*)d_out, N_NODES);
}

// Round 4
// 410.942 us; speedup vs baseline: 1.7442x; 1.0390x over previous
//
#include <hip/hip_runtime.h>
#include <hip/hip_fp16.h>
#include <cstdint>
#include <cstddef>

#define N_NODES 50000
#define N_EDGES 800000
#define DIN_    768
#define H_DIM   128
#define N_REL   3
#define BETA_F  0.05f
#define SLOPE_F 0.2f

static inline int cdiv(int a, int b) { return (a + b - 1) / b; }

typedef __attribute__((ext_vector_type(8))) short bf16x8;
typedef __attribute__((ext_vector_type(8))) unsigned short u16x8;
typedef __attribute__((ext_vector_type(4))) float f32x4;

__device__ __forceinline__ unsigned short f2bf(float f) {
  unsigned u = __builtin_bit_cast(unsigned, f);
  unsigned r = (u + 0x7fffu + ((u >> 16) & 1u)) >> 16;
  return (unsigned short)r;
}
__device__ __forceinline__ float bf2f(unsigned short h) {
  unsigned u = ((unsigned)h) << 16;
  return __builtin_bit_cast(float, u);
}

// ---------------- CSR build ----------------
__global__ void k_count(const int* __restrict__ dst, int* __restrict__ deg, int E) {
  int e = blockIdx.x * blockDim.x + threadIdx.x;
  if (e < E) atomicAdd(&deg[dst[e]], 1);
}

__global__ __launch_bounds__(256) void k_scan1(const int* __restrict__ deg,
                                               int* __restrict__ part, int n) {
  __shared__ int wsum[4];
  int i = blockIdx.x * 256 + threadIdx.x;
  int lane = threadIdx.x & 63, w = threadIdx.x >> 6;
  int v = (i < n) ? deg[i] : 0;
  #pragma unroll
  for (int d = 32; d > 0; d >>= 1) v += __shfl_xor(v, d);
  if (lane == 0) wsum[w] = v;
  __syncthreads();
  if (threadIdx.x == 0) part[blockIdx.x] = wsum[0] + wsum[1] + wsum[2] + wsum[3];
}

__global__ __launch_bounds__(256) void k_scan2(int* __restrict__ part,
                                               int* __restrict__ off, int nb, int n) {
  __shared__ int sh[256];
  int t = threadIdx.x;
  int v = (t < nb) ? part[t] : 0;
  int incl = v;
  sh[t] = incl;
  __syncthreads();
  #pragma unroll
  for (int d = 1; d < 256; d <<= 1) {
    int u = (t >= d) ? sh[t - d] : 0;
    __syncthreads();
    sh[t] += u;
    __syncthreads();
  }
  incl = sh[t];
  if (t < nb) part[t] = incl - v;
  if (t == nb - 1) off[n] = incl;
}

__global__ __launch_bounds__(256) void k_scan3(const int* __restrict__ deg,
                                               const int* __restrict__ part,
                                               int* __restrict__ off,
                                               int* __restrict__ cur, int n) {
  __shared__ int wsum[4];
  int i = blockIdx.x * 256 + threadIdx.x;
  int lane = threadIdx.x & 63, w = threadIdx.x >> 6;
  int v = (i < n) ? deg[i] : 0;
  int incl = v;
  #pragma unroll
  for (int d = 1; d < 64; d <<= 1) {
    int u = __shfl_up(incl, d);
    if (lane >= d) incl += u;
  }
  if (lane == 63) wsum[w] = incl;
  __syncthreads();
  int woff = 0;
  #pragma unroll
  for (int k = 0; k < 4; ++k) woff += (k < w) ? wsum[k] : 0;
  int ex = incl - v + woff + part[blockIdx.x];
  if (i < n) { off[i] = ex; cur[i] = ex; }
}

__global__ void k_fill(const int* __restrict__ dst, int* __restrict__ cur,
                       int* __restrict__ csr, int E) {
  int e = blockIdx.x * blockDim.x + threadIdx.x;
  if (e < E) {
    int p = atomicAdd(&cur[dst[e]], 1);
    csr[p] = e;
  }
}

// ---------------- rel scores ----------------
__global__ __launch_bounds__(128) void k_relscore(const float* __restrict__ rel,
                                                  const float* __restrict__ Wr,
                                                  const float* __restrict__ a,
                                                  float* __restrict__ rs) {
  __shared__ float red[128];
  int k = threadIdx.x;
  for (int t = 0; t < N_REL; ++t) {
    float p = 0.f;
    #pragma unroll
    for (int j = 0; j < 32; ++j) p += rel[t * 32 + j] * Wr[j * H_DIM + k];
    red[k] = p * a[2 * H_DIM + k];
    __syncthreads();
    for (int s = 64; s > 0; s >>= 1) {
      if (k < s) red[k] += red[k + s];
      __syncthreads();
    }
    if (k == 0) rs[t] = red[0];
    __syncthreads();
  }
}

// ---------------- weight prep ----------------
__global__ void k_prep(const float* __restrict__ W, int K,
                       short* __restrict__ th, short* __restrict__ tl) {
  int id = blockIdx.x * 256 + threadIdx.x;
  if (id >= K * 128) return;
  int k = id >> 7, c = id & 127;
  float w = W[id];
  unsigned short h = f2bf(w);
  unsigned short l = f2bf(w - bf2f(h));
  th[(size_t)c * K + k] = (short)h;
  tl[(size_t)c * K + k] = (short)l;
}

// ---------------- split-bf16 MFMA GEMM (+ optional fused fp16 copy) ----------------
#define BM 128
#define BK 64
template <bool BIASRELU, bool W16>
__global__ __launch_bounds__(256, 2) void k_gemm_mfma(const float* __restrict__ A,
                                                      const short* __restrict__ Bth,
                                                      const short* __restrict__ Btl,
                                                      const float* __restrict__ bias,
                                                      float* __restrict__ C,
                                                      __half* __restrict__ C16,
                                                      int n, int K) {
  __shared__ short Ahi[BM * BK], Alo[BM * BK], Bhi[128 * BK], Blo[128 * BK];
  int t = threadIdx.x;
  int l = t & 63, wid = t >> 6;
  int wr = wid >> 1, wc = wid & 1;
  int lr = l & 15, lk = l >> 4;
  int row0 = blockIdx.x * BM;
  f32x4 acc[4][4];
  #pragma unroll
  for (int m = 0; m < 4; ++m)
    #pragma unroll
    for (int nn = 0; nn < 4; ++nn) acc[m][nn] = (f32x4)(0.f);

  for (int k0 = 0; k0 < K; k0 += BK) {
    #pragma unroll
    for (int i = 0; i < 4; ++i) {
      int gid = i * 256 + t;
      int r = gid >> 3, g = gid & 7;
      int gr = row0 + r;
      float4 v0 = make_float4(0.f, 0.f, 0.f, 0.f);
      float4 v1 = make_float4(0.f, 0.f, 0.f, 0.f);
      if (gr < n) {
        const float* ap = A + (size_t)gr * K + k0 + g * 8;
        v0 = *(const float4*)ap;
        v1 = *(const float4*)(ap + 4);
      }
      float f[8] = {v0.x, v0.y, v0.z, v0.w, v1.x, v1.y, v1.z, v1.w};
      u16x8 hv, lv;
      #pragma unroll
      for (int j = 0; j < 8; ++j) {
        unsigned short h = f2bf(f[j]);
        hv[j] = h;
        lv[j] = f2bf(f[j] - bf2f(h));
      }
      int sg = (g ^ (r & 7)) << 3;
      *(u16x8*)&Ahi[r * BK + sg] = hv;
      *(u16x8*)&Alo[r * BK + sg] = lv;
    }
    #pragma unroll
    for (int i = 0; i < 4; ++i) {
      int gid = i * 256 + t;
      int c = gid >> 3, g = gid & 7;
      u16x8 hv = *(const u16x8*)(Bth + (size_t)c * K + k0 + g * 8);
      u16x8 lv = *(const u16x8*)(Btl + (size_t)c * K + k0 + g * 8);
      int sg = (g ^ (c & 7)) << 3;
      *(u16x8*)&Bhi[c * BK + sg] = hv;
      *(u16x8*)&Blo[c * BK + sg] = lv;
    }
    __syncthreads();
    #pragma unroll
    for (int kk = 0; kk < 2; ++kk) {
      int gbase = kk * 4 + lk;
      bf16x8 ah[4], al[4], bh[4], bl[4];
      #pragma unroll
      for (int m = 0; m < 4; ++m) {
        int r = wr * 64 + m * 16 + lr;
        int idx = r * BK + ((gbase ^ (r & 7)) << 3);
        ah[m] = *(const bf16x8*)&Ahi[idx];
        al[m] = *(const bf16x8*)&Alo[idx];
      }
      #pragma unroll
      for (int nn = 0; nn < 4; ++nn) {
        int c = wc * 64 + nn * 16 + lr;
        int idx = c * BK + ((gbase ^ (c & 7)) << 3);
        bh[nn] = *(const bf16x8*)&Bhi[idx];
        bl[nn] = *(const bf16x8*)&Blo[idx];
      }
      #pragma unroll
      for (int m = 0; m < 4; ++m)
        #pragma unroll
        for (int nn = 0; nn < 4; ++nn) {
          acc[m][nn] = __builtin_amdgcn_mfma_f32_16x16x32_bf16(ah[m], bh[nn], acc[m][nn], 0, 0, 0);
          acc[m][nn] = __builtin_amdgcn_mfma_f32_16x16x32_bf16(ah[m], bl[nn], acc[m][nn], 0, 0, 0);
          acc[m][nn] = __builtin_amdgcn_mfma_f32_16x16x32_bf16(al[m], bh[nn], acc[m][nn], 0, 0, 0);
        }
    }
    __syncthreads();
  }
  #pragma unroll
  for (int m = 0; m < 4; ++m) {
    int rbase = row0 + wr * 64 + m * 16 + lk * 4;
    #pragma unroll
    for (int nn = 0; nn < 4; ++nn) {
      int c = wc * 64 + nn * 16 + lr;
      #pragma unroll
      for (int q = 0; q < 4; ++q) {
        int r = rbase + q;
        if (r < n) {
          float v = acc[m][nn][q];
          if (BIASRELU) {
            v += bias[c];
            v = v > 0.f ? v : 0.f;
          }
          C[(size_t)r * 128 + c] = v;
          if (W16) C16[(size_t)r * 128 + c] = __float2half(v);
        }
      }
    }
  }
}

// ---------------- per-node scores ----------------
__global__ __launch_bounds__(256) void k_scores(const float* __restrict__ h,
                                                const float* __restrict__ a,
                                                float* __restrict__ ni,
                                                float* __restrict__ nj, int n) {
  int lane = threadIdx.x & 63;
  int w = threadIdx.x >> 6;
  int row = blockIdx.x * 4 + w;
  if (row >= n) return;
  float2 v = ((const float2*)(h + (size_t)row * H_DIM))[lane];
  float2 ai = ((const float2*)a)[lane];
  float2 aj = ((const float2*)(a + H_DIM))[lane];
  float si = v.x * ai.x + v.y * ai.y;
  float sj = v.x * aj.x + v.y * aj.y;
  #pragma unroll
  for (int d = 32; d > 0; d >>= 1) {
    si += __shfl_xor(si, d);
    sj += __shfl_xor(sj, d);
  }
  if (lane == 0) { ni[row] = si; nj[row] = sj; }
}

// ---------------- edge logits ----------------
__global__ void k_logit(const int* __restrict__ src, const int* __restrict__ dst,
                        const int* __restrict__ et,
                        const float* __restrict__ ni, const float* __restrict__ nj,
                        const float* __restrict__ rs,
                        float* __restrict__ logit, int E) {
  int e = blockIdx.x * blockDim.x + threadIdx.x;
  if (e >= E) return;
  float v = ni[dst[e]] + nj[src[e]] + rs[et[e]];
  logit[e] = v > 0.f ? v : SLOPE_F * v;
}

// ---------------- per-dst softmax + aggregate (fp16 gather) + ELU ----------------
template <int LAYER>
__global__ __launch_bounds__(128) void k_aggregate(const int* __restrict__ off,
                                                   const int* __restrict__ csr,
                                                   const int* __restrict__ src,
                                                   const float* __restrict__ logit,
                                                   const __half* __restrict__ h16,
                                                   float* __restrict__ alpha_io,
                                                   float* __restrict__ hout, int n) {
  __shared__ float l_red[2];
  __shared__ float l_alpha[128];
  __shared__ int   l_src[128];
  int nid = blockIdx.x;
  int t = threadIdx.x;
  int lane = t & 63;
  int w = t >> 6;
  int start = off[nid];
  int deg = off[nid + 1] - start;
  float hv = 0.f;
  if (deg > 0) {
    float m = -INFINITY;
    for (int k = t; k < deg; k += 128) m = fmaxf(m, logit[csr[start + k]]);
    #pragma unroll
    for (int d = 32; d > 0; d >>= 1) m = fmaxf(m, __shfl_xor(m, d));
    if (lane == 0) l_red[w] = m;
    __syncthreads();
    m = fmaxf(l_red[0], l_red[1]);
    __syncthreads();
    float s = 0.f;
    for (int k = t; k < deg; k += 128) s += expf(logit[csr[start + k]] - m);
    #pragma unroll
    for (int d = 32; d > 0; d >>= 1) s += __shfl_xor(s, d);
    if (lane == 0) l_red[w] = s;
    __syncthreads();
    float denom = l_red[0] + l_red[1] + 1e-16f;
    for (int base = 0; base < deg; base += 128) {
      int kk = base + t;
      if (kk < deg) {
        int e = csr[start + kk];
        float al = expf(logit[e] - m) / denom;
        if (LAYER == 1) {
          al = al * (1.f - BETA_F) + BETA_F * alpha_io[e];
        } else {
          alpha_io[e] = al;
        }
        l_alpha[t] = al;
        l_src[t] = src[e];
      }
      __syncthreads();
      int cnt = deg - base; if (cnt > 128) cnt = 128;
      #pragma unroll 4
      for (int k = 0; k < cnt; ++k)
        hv += l_alpha[k] * __half2float(h16[(size_t)l_src[k] * H_DIM + t]);
      __syncthreads();
    }
  }
  hout[(size_t)nid * H_DIM + t] = hv > 0.f ? hv : expm1f(hv);
}

// ---------------- final 128->2 projection ----------------
__global__ __launch_bounds__(256) void k_out(const float* __restrict__ P,
                                             const float* __restrict__ ow,
                                             const float* __restrict__ ob,
                                             float* __restrict__ out, int n) {
  int lane = threadIdx.x & 63;
  int w = threadIdx.x >> 6;
  int row = blockIdx.x * 4 + w;
  if (row >= n) return;
  float2 v  = ((const float2*)(P + (size_t)row * H_DIM))[lane];
  float2 w0 = ((const float2*)ow)[2 * lane];
  float2 w1 = ((const float2*)ow)[2 * lane + 1];
  float s0 = v.x * w0.x + v.y * w1.x;
  float s1 = v.x * w0.y + v.y * w1.y;
  #pragma unroll
  for (int d = 32; d > 0; d >>= 1) {
    s0 += __shfl_xor(s0, d);
    s1 += __shfl_xor(s1, d);
  }
  if (lane == 0) {
    out[row * 2]     = s0 + ob[0];
    out[row * 2 + 1] = s1 + ob[1];
  }
}

extern "C" void kernel_launch(void* const* d_in, const int* in_sizes, int n_in,
                              void* d_out, int out_size, void* d_ws, size_t ws_size,
                              hipStream_t stream) {
  const float* x      = (const float*)d_in[0];
  const int*   ei     = (const int*)d_in[1];
  const int*   et     = (const int*)d_in[2];
  const float* W0     = (const float*)d_in[3];
  const float* Wr0    = (const float*)d_in[4];
  const float* a0     = (const float*)d_in[5];
  const float* rel0   = (const float*)d_in[6];
  const float* W1     = (const float*)d_in[7];
  const float* Wr1    = (const float*)d_in[8];
  const float* a1     = (const float*)d_in[9];
  const float* rel1   = (const float*)d_in[10];
  const float* pool_w = (const float*)d_in[11];
  const float* pool_b = (const float*)d_in[12];
  const float* out_w  = (const float*)d_in[13];
  const float* out_b  = (const float*)d_in[14];

  const int* src = ei;
  const int* dst = ei + N_EDGES;

  char* p = (char*)d_ws;
  auto take = [&](size_t bytes) {
    char* r = p;
    p += (bytes + 511) & ~(size_t)511;
    return r;
  };
  int*   deg    = (int*)take((size_t)N_NODES * 4);
  int*   off    = (int*)take((size_t)(N_NODES + 1) * 4);
  int*   cur    = (int*)take((size_t)N_NODES * 4);
  int*   part   = (int*)take((size_t)256 * 4);
  int*   csr    = (int*)take((size_t)N_EDGES * 4);
  float* logit  = (float*)take((size_t)N_EDGES * 4);
  float* alpha0 = (float*)take((size_t)N_EDGES * 4);
  float* ni     = (float*)take((size_t)N_NODES * 4);
  float* nj     = (float*)take((size_t)N_NODES * 4);
  float* rs     = (float*)take(256);
  short* wt0h   = (short*)take((size_t)DIN_ * 128 * 2);
  short* wt0l   = (short*)take((size_t)DIN_ * 128 * 2);
  short* wt1h   = (short*)take((size_t)128 * 128 * 2);
  short* wt1l   = (short*)take((size_t)128 * 128 * 2);
  short* wph    = (short*)take((size_t)128 * 128 * 2);
  short* wpl    = (short*)take((size_t)128 * 128 * 2);
  float* big1   = (float*)take((size_t)N_NODES * H_DIM * 4);
  float* big2   = (float*)take((size_t)N_NODES * H_DIM * 4);
  __half* h16   = (__half*)take((size_t)N_NODES * H_DIM * 2);

  const int EB = cdiv(N_EDGES, 256);
  const int GB = cdiv(N_NODES, BM);
  const int SB = cdiv(N_NODES, 256);

  // ---- CSR build ----
  hipMemsetAsync(deg, 0, (size_t)N_NODES * 4, stream);
  k_count<<<EB, 256, 0, stream>>>(dst, deg, N_EDGES);
  k_scan1<<<SB, 256, 0, stream>>>(deg, part, N_NODES);
  k_scan2<<<1, 256, 0, stream>>>(part, off, SB, N_NODES);
  k_scan3<<<SB, 256, 0, stream>>>(deg, part, off, cur, N_NODES);
  k_fill<<<EB, 256, 0, stream>>>(dst, cur, csr, N_EDGES);

  // ---- weight prep ----
  k_prep<<<cdiv(DIN_ * 128, 256), 256, 0, stream>>>(W0, DIN_, wt0h, wt0l);
  k_prep<<<cdiv(128 * 128, 256), 256, 0, stream>>>(W1, 128, wt1h, wt1l);
  k_prep<<<cdiv(128 * 128, 256), 256, 0, stream>>>(pool_w, 128, wph, wpl);

  // ---- layer 0 ----
  k_relscore<<<1, 128, 0, stream>>>(rel0, Wr0, a0, rs);
  k_gemm_mfma<false, true><<<GB, 256, 0, stream>>>(x, wt0h, wt0l, nullptr, big1, h16, N_NODES, DIN_);
  k_scores<<<cdiv(N_NODES, 4), 256, 0, stream>>>(big1, a0, ni, nj, N_NODES);
  k_logit<<<EB, 256, 0, stream>>>(src, dst, et, ni, nj, rs, logit, N_EDGES);
  k_aggregate<0><<<N_NODES, 128, 0, stream>>>(off, csr, src, logit, h16, alpha0, big2, N_NODES);

  // ---- layer 1 ----
  k_relscore<<<1, 128, 0, stream>>>(rel1, Wr1, a1, rs);
  k_gemm_mfma<false, true><<<GB, 256, 0, stream>>>(big2, wt1h, wt1l, nullptr, big1, h16, N_NODES, 128);
  k_scores<<<cdiv(N_NODES, 4), 256, 0, stream>>>(big1, a1, ni, nj, N_NODES);
  k_logit<<<EB, 256, 0, stream>>>(src, dst, et, ni, nj, rs, logit, N_EDGES);
  k_aggregate<1><<<N_NODES, 128, 0, stream>>>(off, csr, src, logit, h16, alpha0, big2, N_NODES);

  // ---- head ----
  k_gemm_mfma<true, false><<<GB, 256, 0, stream>>>(big2, wph, wpl, pool_b, big1, nullptr, N_NODES, 128);
  k_out<<<cdiv(N_NODES, 4), 256, 0, stream>>>(big1, out_w, out_b, (float*)d_out, N_NODES);
}

// Round 5
// 400.962 us; speedup vs baseline: 1.7876x; 1.0249x over previous
//
#include <hip/hip_runtime.h>
#include <hip/hip_fp16.h>
#include <cstdint>
#include <cstddef>

#define N_NODES 50000
#define N_EDGES 800000
#define DIN_    768
#define H_DIM   128
#define N_REL   3
#define BETA_F  0.05f
#define SLOPE_F 0.2f

static inline int cdiv(int a, int b) { return (a + b - 1) / b; }

typedef __attribute__((ext_vector_type(8))) short bf16x8;
typedef __attribute__((ext_vector_type(8))) unsigned short u16x8;
typedef __attribute__((ext_vector_type(4))) float f32x4;

__device__ __forceinline__ unsigned short f2bf(float f) {
  unsigned u = __builtin_bit_cast(unsigned, f);
  unsigned r = (u + 0x7fffu + ((u >> 16) & 1u)) >> 16;
  return (unsigned short)r;
}
__device__ __forceinline__ float bf2f(unsigned short h) {
  unsigned u = ((unsigned)h) << 16;
  return __builtin_bit_cast(float, u);
}

// ---------------- CSR build ----------------
__global__ void k_count(const int* __restrict__ dst, int* __restrict__ deg, int E) {
  int e = blockIdx.x * blockDim.x + threadIdx.x;
  if (e < E) atomicAdd(&deg[dst[e]], 1);
}

__global__ __launch_bounds__(256) void k_scan1(const int* __restrict__ deg,
                                               int* __restrict__ part, int n) {
  __shared__ int wsum[4];
  int i = blockIdx.x * 256 + threadIdx.x;
  int lane = threadIdx.x & 63, w = threadIdx.x >> 6;
  int v = (i < n) ? deg[i] : 0;
  #pragma unroll
  for (int d = 32; d > 0; d >>= 1) v += __shfl_xor(v, d);
  if (lane == 0) wsum[w] = v;
  __syncthreads();
  if (threadIdx.x == 0) part[blockIdx.x] = wsum[0] + wsum[1] + wsum[2] + wsum[3];
}

__global__ __launch_bounds__(256) void k_scan2(int* __restrict__ part,
                                               int* __restrict__ off, int nb, int n) {
  __shared__ int sh[256];
  int t = threadIdx.x;
  int v = (t < nb) ? part[t] : 0;
  int incl = v;
  sh[t] = incl;
  __syncthreads();
  #pragma unroll
  for (int d = 1; d < 256; d <<= 1) {
    int u = (t >= d) ? sh[t - d] : 0;
    __syncthreads();
    sh[t] += u;
    __syncthreads();
  }
  incl = sh[t];
  if (t < nb) part[t] = incl - v;
  if (t == nb - 1) off[n] = incl;
}

__global__ __launch_bounds__(256) void k_scan3(const int* __restrict__ deg,
                                               const int* __restrict__ part,
                                               int* __restrict__ off,
                                               int* __restrict__ cur, int n) {
  __shared__ int wsum[4];
  int i = blockIdx.x * 256 + threadIdx.x;
  int lane = threadIdx.x & 63, w = threadIdx.x >> 6;
  int v = (i < n) ? deg[i] : 0;
  int incl = v;
  #pragma unroll
  for (int d = 1; d < 64; d <<= 1) {
    int u = __shfl_up(incl, d);
    if (lane >= d) incl += u;
  }
  if (lane == 63) wsum[w] = incl;
  __syncthreads();
  int woff = 0;
  #pragma unroll
  for (int k = 0; k < 4; ++k) woff += (k < w) ? wsum[k] : 0;
  int ex = incl - v + woff + part[blockIdx.x];
  if (i < n) { off[i] = ex; cur[i] = ex; }
}

__global__ void k_fill(const int* __restrict__ dst, int* __restrict__ cur,
                       int* __restrict__ csr, int E) {
  int e = blockIdx.x * blockDim.x + threadIdx.x;
  if (e < E) {
    int p = atomicAdd(&cur[dst[e]], 1);
    csr[p] = e;
  }
}

// ---------------- rel scores ----------------
__global__ __launch_bounds__(128) void k_relscore(const float* __restrict__ rel,
                                                  const float* __restrict__ Wr,
                                                  const float* __restrict__ a,
                                                  float* __restrict__ rs) {
  __shared__ float red[128];
  int k = threadIdx.x;
  for (int t = 0; t < N_REL; ++t) {
    float p = 0.f;
    #pragma unroll
    for (int j = 0; j < 32; ++j) p += rel[t * 32 + j] * Wr[j * H_DIM + k];
    red[k] = p * a[2 * H_DIM + k];
    __syncthreads();
    for (int s = 64; s > 0; s >>= 1) {
      if (k < s) red[k] += red[k + s];
      __syncthreads();
    }
    if (k == 0) rs[t] = red[0];
    __syncthreads();
  }
}

// ---------------- weight prep ----------------
__global__ void k_prep(const float* __restrict__ W, int K,
                       short* __restrict__ th, short* __restrict__ tl) {
  int id = blockIdx.x * 256 + threadIdx.x;
  if (id >= K * 128) return;
  int k = id >> 7, c = id & 127;
  float w = W[id];
  unsigned short h = f2bf(w);
  unsigned short l = f2bf(w - bf2f(h));
  th[(size_t)c * K + k] = (short)h;
  tl[(size_t)c * K + k] = (short)l;
}

// ---------------- split-bf16 MFMA GEMM, BM=64 for occupancy ----------------
#define BM 64
#define BK 64
template <bool BIASRELU, bool W16>
__global__ __launch_bounds__(256, 3) void k_gemm_mfma(const float* __restrict__ A,
                                                      const short* __restrict__ Bth,
                                                      const short* __restrict__ Btl,
                                                      const float* __restrict__ bias,
                                                      float* __restrict__ C,
                                                      __half* __restrict__ C16,
                                                      int n, int K) {
  __shared__ short Ahi[BM * BK], Alo[BM * BK], Bhi[128 * BK], Blo[128 * BK];
  int t = threadIdx.x;
  int l = t & 63, wid = t >> 6;
  int wr = wid >> 1, wc = wid & 1;   // wave -> 32-row half, 64-col half
  int lr = l & 15, lk = l >> 4;
  int row0 = blockIdx.x * BM;
  f32x4 acc[2][4];
  #pragma unroll
  for (int m = 0; m < 2; ++m)
    #pragma unroll
    for (int nn = 0; nn < 4; ++nn) acc[m][nn] = (f32x4)(0.f);

  for (int k0 = 0; k0 < K; k0 += BK) {
    // ---- stage A: 512 granules of 8 f32 -> hi/lo bf16, swizzled ----
    #pragma unroll
    for (int i = 0; i < 2; ++i) {
      int gid = i * 256 + t;
      int r = gid >> 3, g = gid & 7;
      int gr = row0 + r;
      float4 v0 = make_float4(0.f, 0.f, 0.f, 0.f);
      float4 v1 = make_float4(0.f, 0.f, 0.f, 0.f);
      if (gr < n) {
        const float* ap = A + (size_t)gr * K + k0 + g * 8;
        v0 = *(const float4*)ap;
        v1 = *(const float4*)(ap + 4);
      }
      float f[8] = {v0.x, v0.y, v0.z, v0.w, v1.x, v1.y, v1.z, v1.w};
      u16x8 hv, lv;
      #pragma unroll
      for (int j = 0; j < 8; ++j) {
        unsigned short h = f2bf(f[j]);
        hv[j] = h;
        lv[j] = f2bf(f[j] - bf2f(h));
      }
      int sg = (g ^ (r & 7)) << 3;
      *(u16x8*)&Ahi[r * BK + sg] = hv;
      *(u16x8*)&Alo[r * BK + sg] = lv;
    }
    // ---- stage B: 1024 granules (pre-split bf16), swizzled ----
    #pragma unroll
    for (int i = 0; i < 4; ++i) {
      int gid = i * 256 + t;
      int c = gid >> 3, g = gid & 7;
      u16x8 hv = *(const u16x8*)(Bth + (size_t)c * K + k0 + g * 8);
      u16x8 lv = *(const u16x8*)(Btl + (size_t)c * K + k0 + g * 8);
      int sg = (g ^ (c & 7)) << 3;
      *(u16x8*)&Bhi[c * BK + sg] = hv;
      *(u16x8*)&Blo[c * BK + sg] = lv;
    }
    __syncthreads();
    // ---- MFMA ----
    #pragma unroll
    for (int kk = 0; kk < 2; ++kk) {
      int gbase = kk * 4 + lk;
      bf16x8 ah[2], al[2], bh[4], bl[4];
      #pragma unroll
      for (int m = 0; m < 2; ++m) {
        int r = wr * 32 + m * 16 + lr;
        int idx = r * BK + ((gbase ^ (r & 7)) << 3);
        ah[m] = *(const bf16x8*)&Ahi[idx];
        al[m] = *(const bf16x8*)&Alo[idx];
      }
      #pragma unroll
      for (int nn = 0; nn < 4; ++nn) {
        int c = wc * 64 + nn * 16 + lr;
        int idx = c * BK + ((gbase ^ (c & 7)) << 3);
        bh[nn] = *(const bf16x8*)&Bhi[idx];
        bl[nn] = *(const bf16x8*)&Blo[idx];
      }
      #pragma unroll
      for (int m = 0; m < 2; ++m)
        #pragma unroll
        for (int nn = 0; nn < 4; ++nn) {
          acc[m][nn] = __builtin_amdgcn_mfma_f32_16x16x32_bf16(ah[m], bh[nn], acc[m][nn], 0, 0, 0);
          acc[m][nn] = __builtin_amdgcn_mfma_f32_16x16x32_bf16(ah[m], bl[nn], acc[m][nn], 0, 0, 0);
          acc[m][nn] = __builtin_amdgcn_mfma_f32_16x16x32_bf16(al[m], bh[nn], acc[m][nn], 0, 0, 0);
        }
    }
    __syncthreads();
  }
  #pragma unroll
  for (int m = 0; m < 2; ++m) {
    int rbase = row0 + wr * 32 + m * 16 + lk * 4;
    #pragma unroll
    for (int nn = 0; nn < 4; ++nn) {
      int c = wc * 64 + nn * 16 + lr;
      #pragma unroll
      for (int q = 0; q < 4; ++q) {
        int r = rbase + q;
        if (r < n) {
          float v = acc[m][nn][q];
          if (BIASRELU) {
            v += bias[c];
            v = v > 0.f ? v : 0.f;
          }
          C[(size_t)r * 128 + c] = v;
          if (W16) C16[(size_t)r * 128 + c] = __float2half(v);
        }
      }
    }
  }
}

// ---------------- per-node scores ----------------
__global__ __launch_bounds__(256) void k_scores(const float* __restrict__ h,
                                                const float* __restrict__ a,
                                                float* __restrict__ ni,
                                                float* __restrict__ nj, int n) {
  int lane = threadIdx.x & 63;
  int w = threadIdx.x >> 6;
  int row = blockIdx.x * 4 + w;
  if (row >= n) return;
  float2 v = ((const float2*)(h + (size_t)row * H_DIM))[lane];
  float2 ai = ((const float2*)a)[lane];
  float2 aj = ((const float2*)(a + H_DIM))[lane];
  float si = v.x * ai.x + v.y * ai.y;
  float sj = v.x * aj.x + v.y * aj.y;
  #pragma unroll
  for (int d = 32; d > 0; d >>= 1) {
    si += __shfl_xor(si, d);
    sj += __shfl_xor(sj, d);
  }
  if (lane == 0) { ni[row] = si; nj[row] = sj; }
}

// ---------------- edge logits ----------------
__global__ void k_logit(const int* __restrict__ src, const int* __restrict__ dst,
                        const int* __restrict__ et,
                        const float* __restrict__ ni, const float* __restrict__ nj,
                        const float* __restrict__ rs,
                        float* __restrict__ logit, int E) {
  int e = blockIdx.x * blockDim.x + threadIdx.x;
  if (e >= E) return;
  float v = ni[dst[e]] + nj[src[e]] + rs[et[e]];
  logit[e] = v > 0.f ? v : SLOPE_F * v;
}

// ---------------- per-dst softmax + aggregate (fp16 gather) + ELU ----------------
template <int LAYER>
__global__ __launch_bounds__(128) void k_aggregate(const int* __restrict__ off,
                                                   const int* __restrict__ csr,
                                                   const int* __restrict__ src,
                                                   const float* __restrict__ logit,
                                                   const __half* __restrict__ h16,
                                                   float* __restrict__ alpha_io,
                                                   float* __restrict__ hout, int n) {
  __shared__ float l_red[2];
  __shared__ float l_alpha[128];
  __shared__ int   l_src[128];
  int nid = blockIdx.x;
  int t = threadIdx.x;
  int lane = t & 63;
  int w = t >> 6;
  int start = off[nid];
  int deg = off[nid + 1] - start;
  float hv = 0.f;
  if (deg > 0) {
    float m = -INFINITY;
    for (int k = t; k < deg; k += 128) m = fmaxf(m, logit[csr[start + k]]);
    #pragma unroll
    for (int d = 32; d > 0; d >>= 1) m = fmaxf(m, __shfl_xor(m, d));
    if (lane == 0) l_red[w] = m;
    __syncthreads();
    m = fmaxf(l_red[0], l_red[1]);
    __syncthreads();
    float s = 0.f;
    for (int k = t; k < deg; k += 128) s += expf(logit[csr[start + k]] - m);
    #pragma unroll
    for (int d = 32; d > 0; d >>= 1) s += __shfl_xor(s, d);
    if (lane == 0) l_red[w] = s;
    __syncthreads();
    float denom = l_red[0] + l_red[1] + 1e-16f;
    for (int base = 0; base < deg; base += 128) {
      int kk = base + t;
      if (kk < deg) {
        int e = csr[start + kk];
        float al = expf(logit[e] - m) / denom;
        if (LAYER == 1) {
          al = al * (1.f - BETA_F) + BETA_F * alpha_io[e];
        } else {
          alpha_io[e] = al;
        }
        l_alpha[t] = al;
        l_src[t] = src[e];
      }
      __syncthreads();
      int cnt = deg - base; if (cnt > 128) cnt = 128;
      #pragma unroll 4
      for (int k = 0; k < cnt; ++k)
        hv += l_alpha[k] * __half2float(h16[(size_t)l_src[k] * H_DIM + t]);
      __syncthreads();
    }
  }
  hout[(size_t)nid * H_DIM + t] = hv > 0.f ? hv : expm1f(hv);
}

// ---------------- final 128->2 projection ----------------
__global__ __launch_bounds__(256) void k_out(const float* __restrict__ P,
                                             const float* __restrict__ ow,
                                             const float* __restrict__ ob,
                                             float* __restrict__ out, int n) {
  int lane = threadIdx.x & 63;
  int w = threadIdx.x >> 6;
  int row = blockIdx.x * 4 + w;
  if (row >= n) return;
  float2 v  = ((const float2*)(P + (size_t)row * H_DIM))[lane];
  float2 w0 = ((const float2*)ow)[2 * lane];
  float2 w1 = ((const float2*)ow)[2 * lane + 1];
  float s0 = v.x * w0.x + v.y * w1.x;
  float s1 = v.x * w0.y + v.y * w1.y;
  #pragma unroll
  for (int d = 32; d > 0; d >>= 1) {
    s0 += __shfl_xor(s0, d);
    s1 += __shfl_xor(s1, d);
  }
  if (lane == 0) {
    out[row * 2]     = s0 + ob[0];
    out[row * 2 + 1] = s1 + ob[1];
  }
}

extern "C" void kernel_launch(void* const* d_in, const int* in_sizes, int n_in,
                              void* d_out, int out_size, void* d_ws, size_t ws_size,
                              hipStream_t stream) {
  const float* x      = (const float*)d_in[0];
  const int*   ei     = (const int*)d_in[1];
  const int*   et     = (const int*)d_in[2];
  const float* W0     = (const float*)d_in[3];
  const float* Wr0    = (const float*)d_in[4];
  const float* a0     = (const float*)d_in[5];
  const float* rel0   = (const float*)d_in[6];
  const float* W1     = (const float*)d_in[7];
  const float* Wr1    = (const float*)d_in[8];
  const float* a1     = (const float*)d_in[9];
  const float* rel1   = (const float*)d_in[10];
  const float* pool_w = (const float*)d_in[11];
  const float* pool_b = (const float*)d_in[12];
  const float* out_w  = (const float*)d_in[13];
  const float* out_b  = (const float*)d_in[14];

  const int* src = ei;
  const int* dst = ei + N_EDGES;

  char* p = (char*)d_ws;
  auto take = [&](size_t bytes) {
    char* r = p;
    p += (bytes + 511) & ~(size_t)511;
    return r;
  };
  int*   deg    = (int*)take((size_t)N_NODES * 4);
  int*   off    = (int*)take((size_t)(N_NODES + 1) * 4);
  int*   cur    = (int*)take((size_t)N_NODES * 4);
  int*   part   = (int*)take((size_t)256 * 4);
  int*   csr    = (int*)take((size_t)N_EDGES * 4);
  float* logit  = (float*)take((size_t)N_EDGES * 4);
  float* alpha0 = (float*)take((size_t)N_EDGES * 4);
  float* ni     = (float*)take((size_t)N_NODES * 4);
  float* nj     = (float*)take((size_t)N_NODES * 4);
  float* rs     = (float*)take(256);
  short* wt0h   = (short*)take((size_t)DIN_ * 128 * 2);
  short* wt0l   = (short*)take((size_t)DIN_ * 128 * 2);
  short* wt1h   = (short*)take((size_t)128 * 128 * 2);
  short* wt1l   = (short*)take((size_t)128 * 128 * 2);
  short* wph    = (short*)take((size_t)128 * 128 * 2);
  short* wpl    = (short*)take((size_t)128 * 128 * 2);
  float* big1   = (float*)take((size_t)N_NODES * H_DIM * 4);
  float* big2   = (float*)take((size_t)N_NODES * H_DIM * 4);
  __half* h16   = (__half*)take((size_t)N_NODES * H_DIM * 2);

  const int EB = cdiv(N_EDGES, 256);
  const int GB = cdiv(N_NODES, BM);
  const int SB = cdiv(N_NODES, 256);

  // ---- CSR build ----
  hipMemsetAsync(deg, 0, (size_t)N_NODES * 4, stream);
  k_count<<<EB, 256, 0, stream>>>(dst, deg, N_EDGES);
  k_scan1<<<SB, 256, 0, stream>>>(deg, part, N_NODES);
  k_scan2<<<1, 256, 0, stream>>>(part, off, SB, N_NODES);
  k_scan3<<<SB, 256, 0, stream>>>(deg, part, off, cur, N_NODES);
  k_fill<<<EB, 256, 0, stream>>>(dst, cur, csr, N_EDGES);

  // ---- weight prep ----
  k_prep<<<cdiv(DIN_ * 128, 256), 256, 0, stream>>>(W0, DIN_, wt0h, wt0l);
  k_prep<<<cdiv(128 * 128, 256), 256, 0, stream>>>(W1, 128, wt1h, wt1l);
  k_prep<<<cdiv(128 * 128, 256), 256, 0, stream>>>(pool_w, 128, wph, wpl);

  // ---- layer 0 ----
  k_relscore<<<1, 128, 0, stream>>>(rel0, Wr0, a0, rs);
  k_gemm_mfma<false, true><<<GB, 256, 0, stream>>>(x, wt0h, wt0l, nullptr, big1, h16, N_NODES, DIN_);
  k_scores<<<cdiv(N_NODES, 4), 256, 0, stream>>>(big1, a0, ni, nj, N_NODES);
  k_logit<<<EB, 256, 0, stream>>>(src, dst, et, ni, nj, rs, logit, N_EDGES);
  k_aggregate<0><<<N_NODES, 128, 0, stream>>>(off, csr, src, logit, h16, alpha0, big2, N_NODES);

  // ---- layer 1 ----
  k_relscore<<<1, 128, 0, stream>>>(rel1, Wr1, a1, rs);
  k_gemm_mfma<false, true><<<GB, 256, 0, stream>>>(big2, wt1h, wt1l, nullptr, big1, h16, N_NODES, 128);
  k_scores<<<cdiv(N_NODES, 4), 256, 0, stream>>>(big1, a1, ni, nj, N_NODES);
  k_logit<<<EB, 256, 0, stream>>>(src, dst, et, ni, nj, rs, logit, N_EDGES);
  k_aggregate<1><<<N_NODES, 128, 0, stream>>>(off, csr, src, logit, h16, alpha0, big2, N_NODES);

  // ---- head ----
  k_gemm_mfma<true, false><<<GB, 256, 0, stream>>>(big2, wph, wpl, pool_b, big1, nullptr, N_NODES, 128);
  k_out<<<cdiv(N_NODES, 4), 256, 0, stream>>>(big1, out_w, out_b, (float*)d_out, N_NODES);
}